// Round 6
// baseline (3615.303 us; speedup 1.0000x reference)
//
#include <hip/hip_runtime.h>
#include <hip/hip_fp16.h>
#include <math.h>

// AcousticRadianceTransfer v6 — FREQUENCY-DOMAIN LDS-resident SpMV.
// Rounds 2-5 established a hard ~0.1 random-lines/cyc/CU gather ceiling for
// the time-domain [24000 x 1600] state (12M line-requests/bounce -> 1.5 ms
// floor). Fix the algebra instead: per rfft bin k the bounce chain is a
// 24000-vector iteration x <- A (D_k x) with diagonal complex D_k; a bf16c
// x is 94 KB and lives in LDS for all 8 bounces. Entry fee: factored DFT
// (1600 = 25 x 64) of R0, and an 801-bin irfft of the scalar spectrum yhat.

static constexpr float kSR = 16000.0f;
static constexpr int   kL = 1600;
static constexpr int   kNRad = 24000;
static constexpr int   kNNZ = 480000;
static constexpr int   kNPatch = 256;
static constexpr int   kNF = 801;          // rfft bins
static constexpr int   kNB = 8;            // bounces
static constexpr float kLogGamma = -6.907755278982137f; // ln(0.001)

using u32 = unsigned int;
using u16 = unsigned short;

// ---- packing helpers -------------------------------------------------------
__device__ __forceinline__ u16 f2bf(float f) {
    u32 u = __float_as_uint(f);
    u32 r = u + 0x7fffu + ((u >> 16) & 1u);   // RTN-even
    return (u16)(r >> 16);
}
__device__ __forceinline__ float bflo(u32 w) { return __uint_as_float(w << 16); }
__device__ __forceinline__ float bfhi(u32 w) { return __uint_as_float(w & 0xffff0000u); }
__device__ __forceinline__ u32 pk_bf(float re, float im) {
    return ((u32)f2bf(im) << 16) | (u32)f2bf(re);
}
__device__ __forceinline__ float h2f(u32 bits) {
    return __half2float(__ushort_as_half((u16)bits));
}
__device__ __forceinline__ u32 pk_h(float re, float im) {
    return ((u32)__half_as_ushort(__float2half(im)) << 16)
         | (u32)__half_as_ushort(__float2half(re));
}

// ---------------- CSR build + degree sort (descending) ----------------------

__global__ void k_hist(const int* __restrict__ row, int* __restrict__ cnt) {
    int e = blockIdx.x * 256 + threadIdx.x;
    if (e < kNNZ) atomicAdd(&cnt[row[e]], 1);
}

__global__ void k_deghist(const int* __restrict__ cnt, int* __restrict__ degcnt) {
    int i = blockIdx.x * 256 + threadIdx.x;
    if (i < kNRad) atomicAdd(&degcnt[min(cnt[i], 63)], 1);
}

__global__ void k_degscan(int* __restrict__ degcnt, int* __restrict__ degcur) {
    if (threadIdx.x == 0) {
        int s = 0;
        for (int b = 63; b >= 0; --b) {     // DESCENDING degree order
            int c = degcnt[b];
            degcnt[b] = s; degcur[b] = s; s += c;
        }
    }
}

__global__ void k_perm(const int* __restrict__ cnt, int* __restrict__ degcur,
                       int* __restrict__ perm, int* __restrict__ iperm) {
    int i = blockIdx.x * 256 + threadIdx.x;
    if (i >= kNRad) return;
    int b = min(cnt[i], 63);
    int pos = atomicAdd(&degcur[b], 1);
    perm[pos] = i;
    iperm[i] = pos;
}

__global__ void k_scan2(const int* __restrict__ cnt, const int* __restrict__ perm,
                        int* __restrict__ rowptr, int* __restrict__ cursor) {
    __shared__ int s[256];
    __shared__ int carry_s;
    int tid = threadIdx.x;
    if (tid == 0) carry_s = 0;
    __syncthreads();
    for (int base = 0; base < kNRad; base += 256) {
        int i = base + tid;
        int v = (i < kNRad) ? cnt[perm[i]] : 0;
        s[tid] = v;
        __syncthreads();
        for (int off = 1; off < 256; off <<= 1) {
            int t = (tid >= off) ? s[tid - off] : 0;
            __syncthreads();
            s[tid] += t;
            __syncthreads();
        }
        int incl = s[tid];
        int c = carry_s;
        if (i < kNRad) {
            int ex = c + incl - v;
            rowptr[i] = ex;
            cursor[i] = ex;
        }
        __syncthreads();
        if (tid == 255) carry_s = c + incl;
        __syncthreads();
    }
    if (tid == 0) rowptr[kNRad] = carry_s;
}

__global__ void k_scatter(const float* __restrict__ absorb,
                          const float* __restrict__ scat,
                          const float* __restrict__ basis,
                          const int* __restrict__ row,
                          const int* __restrict__ col,
                          const int* __restrict__ rid,
                          const int* __restrict__ iperm,
                          int* __restrict__ cursor,
                          u32* __restrict__ epack) {
    int e = blockIdx.x * 256 + threadIdx.x;
    if (e >= kNNZ) return;
    int rd = rid[e];
    float v = (scat[rd] * basis[e] + scat[kNPatch + rd] * basis[kNNZ + e]) * absorb[rd];
    int p = iperm[row[e]];
    int pos = atomicAdd(&cursor[p], 1);
    u32 hv = (u32)__half_as_ushort(__float2half(v));
    epack[pos] = (hv << 16) | (u32)col[e];   // col = ORIGINAL id (< 24000)
}

__global__ void k_decay(const int* __restrict__ delay,
                        float* __restrict__ decay, int* __restrict__ dmod) {
    int i = blockIdx.x * 256 + threadIdx.x;
    if (i >= kNRad) return;
    int d = delay[i];
    decay[i] = expf(kLogGamma * (float)d / kSR);
    dmod[i] = d % kL;
}

// ---- per-thread row assignment (snake over descending-degree strata) -------
// stratum i, thread t -> sorted index i*1024 + (i odd ? 1023-t : t).
// Valid for all i<23; i==23 valid iff tid >= 576. MUST match k_build/k_freq.

__global__ void k_build(const int* __restrict__ rowptr,
                        const int* __restrict__ perm,
                        const u32* __restrict__ epack,
                        u32* __restrict__ rowmeta,
                        u32* __restrict__ edata) {
    int t = threadIdx.x;   // single block of 1024
    int j = 0;
    for (int i = 0; i < 24; ++i) {
        int sidx = i * 1024 + ((i & 1) ? (1023 - t) : t);
        u32 meta = 0;
        if (sidx < kNRad) {
            int e0 = rowptr[sidx], e1 = rowptr[sidx + 1];
            meta = ((u32)(e1 - e0) << 16) | (u32)perm[sidx];
            for (int e = e0; e < e1; ++e) {
                edata[j * 1024 + t] = epack[e];
                ++j;
            }
        }
        rowmeta[i * 1024 + t] = meta;
    }
}

// ---- stage A: 25-point DFTs. G[u][r][s] = sum_q x[r,64q+s] w25^{uq} (f16c) -

__global__ __launch_bounds__(256) void k_dftA(const float* __restrict__ rad,
                                              u32* __restrict__ G) {
    __shared__ float twc[625], tws[625];
    int tid = threadIdx.x;
    for (int idx = tid; idx < 625; idx += 256) {
        int u = idx / 25, q = idx - u * 25;
        float a = 2.0f * (float)((u * q) % 25) / 25.0f;
        twc[idx] = cospif(a);
        tws[idx] = -sinpif(a);
    }
    __syncthreads();
    int wv = tid >> 6, lane = tid & 63;
    int r = blockIdx.x * 4 + wv;
    float xq[25];
#pragma unroll
    for (int q = 0; q < 25; ++q) {
        int m = q * 64 + lane;
        xq[q] = rad[(size_t)r * kL + m] * expf(kLogGamma * (float)m / kSR);
    }
#pragma unroll 1
    for (int u = 0; u < 25; ++u) {
        float re = 0.f, im = 0.f;
#pragma unroll
        for (int q = 0; q < 25; ++q) {
            re = fmaf(xq[q], twc[u * 25 + q], re);
            im = fmaf(xq[q], tws[u * 25 + q], im);
        }
        G[((size_t)u * kNRad + r) * 64 + lane] = pk_h(re, im);
    }
}

// ---- stage B: XF[k][r] = sum_s G[k%25][r][s] e^{-2pi i k s/1600} (bf16c) ---

__global__ __launch_bounds__(256) void k_dftB(const u32* __restrict__ G,
                                              u32* __restrict__ XF) {
    __shared__ float twc[64], tws[64];
    int bid = blockIdx.x;
    int k = bid >> 2, chunk = bid & 3;
    int tid = threadIdx.x;
    if (tid < 64) {
        int m = (k * tid) % kL;
        float a = (float)m / 800.0f;
        twc[tid] = cospif(a);
        tws[tid] = -sinpif(a);
    }
    __syncthreads();
    int u = k % 25;
    for (int rr = tid; rr < 6000; rr += 256) {
        int r = chunk * 6000 + rr;
        const uint4* gp = (const uint4*)(G + ((size_t)u * kNRad + r) * 64);
        float re = 0.f, im = 0.f;
#pragma unroll 4
        for (int jj = 0; jj < 16; ++jj) {
            uint4 q = gp[jj];
            u32 zz[4] = {q.x, q.y, q.z, q.w};
#pragma unroll
            for (int c2 = 0; c2 < 4; ++c2) {
                int s = jj * 4 + c2;
                float gr = h2f(zz[c2] & 0xffffu), gi = h2f(zz[c2] >> 16);
                float c = twc[s], sn = tws[s];       // (cos, -sin)
                re += gr * c - gi * sn;
                im += gr * sn + gi * c;
            }
        }
        XF[(size_t)k * kNRad + r] = pk_bf(re, im);
    }
}

// ---- the core: per-frequency 8-bounce LDS-resident SpMV --------------------

__global__ __launch_bounds__(1024) void k_freq(const u32* __restrict__ XF,
                                               const u32* __restrict__ rowmeta,
                                               const u32* __restrict__ edata,
                                               const float* __restrict__ w,
                                               const float* __restrict__ decay,
                                               const int* __restrict__ dmod,
                                               float* __restrict__ yhat) {
    extern __shared__ u32 lds[];
    u32* ldsx = lds;                         // 24000 x bf16c
    float* red = (float*)(lds + kNRad);      // 32 floats
    int k = blockIdx.x, tid = threadIdx.x;
    const float kinv = 1.0f / 800.0f;
    float yre = 0.f, yim = 0.f;

    // load x0 = XF[k,:], accumulate y0 = w^T x0, store z0 = D_k x0
    for (int r = tid; r < kNRad; r += 1024) {
        u32 xz = XF[(size_t)k * kNRad + r];
        float xr = bflo(xz), xi = bfhi(xz);
        float wr = w[r];
        yre = fmaf(wr, xr, yre); yim = fmaf(wr, xi, yim);
        int m = (dmod[r] * k) % kL;
        float a = (float)m * kinv;
        float c = cospif(a), s = sinpif(a);
        float dc = decay[r];
        float dre = dc * c, dim = -dc * s;
        ldsx[r] = pk_bf(dre * xr - dim * xi, dre * xi + dim * xr);
    }
    __syncthreads();

    for (int b = 0; b < kNB; ++b) {
        float nzr[24], nzi[24];
        int j = 0;
#pragma unroll
        for (int i = 0; i < 24; ++i) {
            u32 meta = rowmeta[i * 1024 + tid];  // 0 for invalid stratum
            int deg = (int)(meta >> 16);
            int orow = (int)(meta & 0xffffu);
            float ar = 0.f, ai = 0.f;
            int e = 0;
            for (; e + 4 <= deg; e += 4) {
                u32 u0 = edata[(j + 0) * 1024 + tid];
                u32 u1 = edata[(j + 1) * 1024 + tid];
                u32 u2 = edata[(j + 2) * 1024 + tid];
                u32 u3 = edata[(j + 3) * 1024 + tid];
                u32 z0 = ldsx[u0 & 0xffffu];
                u32 z1 = ldsx[u1 & 0xffffu];
                u32 z2 = ldsx[u2 & 0xffffu];
                u32 z3 = ldsx[u3 & 0xffffu];
                float v0 = h2f(u0 >> 16), v1 = h2f(u1 >> 16);
                float v2 = h2f(u2 >> 16), v3 = h2f(u3 >> 16);
                ar = fmaf(v0, bflo(z0), ar); ai = fmaf(v0, bfhi(z0), ai);
                ar = fmaf(v1, bflo(z1), ar); ai = fmaf(v1, bfhi(z1), ai);
                ar = fmaf(v2, bflo(z2), ar); ai = fmaf(v2, bfhi(z2), ai);
                ar = fmaf(v3, bflo(z3), ar); ai = fmaf(v3, bfhi(z3), ai);
                j += 4;
            }
            for (; e < deg; ++e, ++j) {
                u32 u = edata[j * 1024 + tid];
                u32 z = ldsx[u & 0xffffu];
                float v = h2f(u >> 16);
                ar = fmaf(v, bflo(z), ar); ai = fmaf(v, bfhi(z), ai);
            }
            float wr = w[orow];
            yre = fmaf(wr, ar, yre); yim = fmaf(wr, ai, yim);
            int m = (dmod[orow] * k) % kL;
            float a = (float)m * kinv;
            float c = cospif(a), s = sinpif(a);
            float dc = decay[orow];
            float dre = dc * c, dim = -dc * s;
            nzr[i] = dre * ar - dim * ai;
            nzi[i] = dre * ai + dim * ar;
        }
        __syncthreads();
#pragma unroll
        for (int i = 0; i < 24; ++i) {
            bool valid = (i < 23) || (tid >= 576);
            if (valid) {
                u32 meta = rowmeta[i * 1024 + tid];
                ldsx[meta & 0xffffu] = pk_bf(nzr[i], nzi[i]);
            }
        }
        __syncthreads();
    }

    // block-reduce y
#pragma unroll
    for (int m = 1; m <= 32; m <<= 1) {
        yre += __shfl_xor(yre, m, 64);
        yim += __shfl_xor(yim, m, 64);
    }
    int wv = tid >> 6, lane = tid & 63;
    if (lane == 0) { red[wv * 2] = yre; red[wv * 2 + 1] = yim; }
    __syncthreads();
    if (tid == 0) {
        float sr = 0.f, si = 0.f;
        for (int i = 0; i < 16; ++i) { sr += red[i * 2]; si += red[i * 2 + 1]; }
        yhat[2 * k] = sr;
        yhat[2 * k + 1] = si;
    }
}

// ---- finish: irfft(yhat)[n] * exp(env)/fsm ---------------------------------

__global__ void k_final(const float* __restrict__ yhat,
                        const float* __restrict__ env,
                        float* __restrict__ out) {
    int n = blockIdx.x * 256 + threadIdx.x;
    if (n >= kL) return;
    float acc = yhat[0];
    acc += (n & 1) ? -yhat[1600] : yhat[1600];   // Nyquist bin (real)
    for (int k = 1; k < 800; ++k) {
        int m = (k * n) % kL;
        float a = (float)m / 800.0f;
        float c = cospif(a), s = sinpif(a);
        acc += 2.0f * (yhat[2 * k] * c - yhat[2 * k + 1] * s);
    }
    acc *= (1.0f / 1600.0f);
    out[n] = acc * expf(env[n] - kLogGamma * (float)n / kSR);
}

extern "C" void kernel_launch(void* const* d_in, const int* in_sizes, int n_in,
                              void* d_out, int out_size, void* d_ws, size_t ws_size,
                              hipStream_t stream) {
    const float* absorb = (const float*)d_in[0];
    const float* scat   = (const float*)d_in[1];
    const float* rad    = (const float*)d_in[2];
    const float* w      = (const float*)d_in[3];
    const float* env    = (const float*)d_in[4];
    const float* basis  = (const float*)d_in[5];
    const int*   srow   = (const int*)d_in[6];
    const int*   scol   = (const int*)d_in[7];
    const int*   srid   = (const int*)d_in[8];
    const int*   delay  = (const int*)d_in[9];

    char* ws = (char*)d_ws;
    size_t off = 0;
    auto alloc = [&](size_t bytes) -> char* {
        char* p = ws + off;
        off += (bytes + 255) & ~size_t(255);
        return p;
    };
    u32*  G      = (u32*)alloc((size_t)25 * kNRad * 64 * 4);   // 153.6 MB
    u32*  XF     = (u32*)alloc((size_t)kNF * kNRad * 4);       // 76.9 MB
    u32*  edata  = (u32*)alloc((size_t)1024 * 1024 * 4);       // 4 MB
    u32*  epack  = (u32*)alloc((size_t)kNNZ * 4);
    u32*  rowmeta= (u32*)alloc((size_t)24 * 1024 * 4);
    float* yhat  = (float*)alloc((size_t)1602 * 4);
    int*  rowptr = (int*)alloc((size_t)(kNRad + 1) * 4);
    int*  cursor = (int*)alloc((size_t)kNRad * 4);
    int*  cnt    = (int*)alloc((size_t)kNRad * 4);
    int*  perm   = (int*)alloc((size_t)kNRad * 4);
    int*  iperm  = (int*)alloc((size_t)kNRad * 4);
    float* decay = (float*)alloc((size_t)kNRad * 4);
    int*  dmod   = (int*)alloc((size_t)kNRad * 4);
    int*  degcnt = (int*)alloc(64 * 4);
    int*  degcur = (int*)alloc(64 * 4);
    (void)ws_size; (void)in_sizes; (void)n_in; (void)out_size; (void)scol;

    hipMemsetAsync(cnt, 0, (size_t)kNRad * 4, stream);
    hipMemsetAsync(degcnt, 0, 64 * 4, stream);

    k_hist<<<(kNNZ + 255) / 256, 256, 0, stream>>>(srow, cnt);
    k_deghist<<<(kNRad + 255) / 256, 256, 0, stream>>>(cnt, degcnt);
    k_degscan<<<1, 64, 0, stream>>>(degcnt, degcur);
    k_perm<<<(kNRad + 255) / 256, 256, 0, stream>>>(cnt, degcur, perm, iperm);
    k_scan2<<<1, 256, 0, stream>>>(cnt, perm, rowptr, cursor);
    k_decay<<<(kNRad + 255) / 256, 256, 0, stream>>>(delay, decay, dmod);
    k_scatter<<<(kNNZ + 255) / 256, 256, 0, stream>>>(absorb, scat, basis, srow,
                                                      scol, srid, iperm, cursor, epack);
    k_build<<<1, 1024, 0, stream>>>(rowptr, perm, epack, rowmeta, edata);

    k_dftA<<<kNRad / 4, 256, 0, stream>>>(rad, G);
    k_dftB<<<kNF * 4, 256, 0, stream>>>(G, XF);

    static bool attr_set = false;
    if (!attr_set) {
        hipFuncSetAttribute((const void*)k_freq,
                            hipFuncAttributeMaxDynamicSharedMemorySize, 98304);
        attr_set = true;
    }
    size_t ldsbytes = (size_t)kNRad * 4 + 256;
    k_freq<<<kNF, 1024, ldsbytes, stream>>>(XF, rowmeta, edata, w, decay, dmod, yhat);

    k_final<<<(kL + 255) / 256, 256, 0, stream>>>(yhat, env, (float*)d_out);
}